// Round 1
// 4581.011 us; speedup vs baseline: 1.9342x; 1.9342x over previous
//
#include <hip/hip_runtime.h>
#include <stdint.h>

#define B_ 64
#define T_ 256
#define H_ 1024
#define L_ 4
#define O_ 1024
#define LN_EPS 1e-5f
#define RING 4

typedef short v8s __attribute__((ext_vector_type(8)));
typedef float v4f __attribute__((ext_vector_type(4)));
typedef unsigned long long u64t;

__device__ __forceinline__ unsigned short f2bf(float f) {
  union { float f; unsigned u; } v; v.f = f;
  unsigned r = (v.u + 0x7FFFu + ((v.u >> 16) & 1u)) >> 16;  // RNE
  return (unsigned short)r;
}
__device__ __forceinline__ float bf2f(unsigned short u) {
  union { unsigned u; float f; } v; v.u = ((unsigned)u) << 16; return v.f;
}
__device__ __forceinline__ float tanh_fast(float x) {
  float e = __expf(2.0f * x);
  return 1.0f - 2.0f / (e + 1.0f);   // -> -1/+1 correctly at +-inf
}

// Swizzled LDS index for 16x1024 bf16 tiles (16B granules), bijective per row.
__device__ __forceinline__ int hswz(int row, int kq) {
  return ((row << 7) + ((kq ^ (kq >> 4) ^ row) & 127)) << 3;
}

__device__ __forceinline__ void poll_ge(const int* p, int v) {
  int it = 0;
  while (__hip_atomic_load(p, __ATOMIC_RELAXED, __HIP_MEMORY_SCOPE_AGENT) < v) {
    __builtin_amdgcn_s_sleep(1);
    if (++it > (1 << 20)) break;   // safety valve: garbage beats hang
  }
}

// ---------------- fp32 -> bf16 bulk convert (vec4) ----------------
__global__ void k_f2b(const float* __restrict__ src, unsigned short* __restrict__ dst, int n4) {
  int i = blockIdx.x * blockDim.x + threadIdx.x;
  int stride = gridDim.x * blockDim.x;
  for (; i < n4; i += stride) {
    float4 v = *(const float4*)(src + 4 * (size_t)i);
    union { unsigned short u[4]; uint2 q; } p;
    p.u[0] = f2bf(v.x); p.u[1] = f2bf(v.y); p.u[2] = f2bf(v.z); p.u[3] = f2bf(v.w);
    *(uint2*)(dst + 4 * (size_t)i) = p.q;
  }
}

// ---------------- bf16 GEMM: C[M=16384][1024] = X @ W^T + bias ----------------
__launch_bounds__(256, 2)
__global__ void k_gemm(const unsigned short* __restrict__ Xb,
                       const unsigned short* __restrict__ Wb,
                       const float* __restrict__ bias,
                       float* __restrict__ Cout, int swap_rows) {
  __shared__ short As[128][40];
  __shared__ short Bs[128][40];
  int bm = blockIdx.x >> 3, bn = blockIdx.x & 7;
  int row0 = bm * 128, col0 = bn * 128;
  int tid = threadIdx.x, lane = tid & 63, w = tid >> 6;
  int wm = w >> 1, wn = w & 1;
  int m15 = lane & 15, quad = lane >> 4;
  v4f acc[4][4];
  #pragma unroll
  for (int a = 0; a < 4; ++a)
    #pragma unroll
    for (int b = 0; b < 4; ++b) acc[a][b] = (v4f){0.f, 0.f, 0.f, 0.f};

  int srow = tid >> 1, sseg = tid & 1;
  const unsigned short* gA = Xb + (size_t)(row0 + srow) * 1024 + sseg * 16;
  const unsigned short* gB = Wb + (size_t)(col0 + srow) * 1024 + sseg * 16;

  for (int kb = 0; kb < 32; ++kb) {
    v8s a0 = *(const v8s*)(gA + kb * 32);
    v8s a1 = *(const v8s*)(gA + kb * 32 + 8);
    v8s b0 = *(const v8s*)(gB + kb * 32);
    v8s b1 = *(const v8s*)(gB + kb * 32 + 8);
    *(v8s*)&As[srow][sseg * 16]     = a0;
    *(v8s*)&As[srow][sseg * 16 + 8] = a1;
    *(v8s*)&Bs[srow][sseg * 16]     = b0;
    *(v8s*)&Bs[srow][sseg * 16 + 8] = b1;
    __syncthreads();
    v8s af[4], bfr[4];
    #pragma unroll
    for (int mt = 0; mt < 4; ++mt) af[mt]  = *(v8s*)&As[wm * 64 + mt * 16 + m15][quad * 8];
    #pragma unroll
    for (int nt = 0; nt < 4; ++nt) bfr[nt] = *(v8s*)&Bs[wn * 64 + nt * 16 + m15][quad * 8];
    #pragma unroll
    for (int mt = 0; mt < 4; ++mt)
      #pragma unroll
      for (int nt = 0; nt < 4; ++nt)
        acc[mt][nt] = __builtin_amdgcn_mfma_f32_16x16x32_bf16(af[mt], bfr[nt], acc[mt][nt], 0, 0, 0);
    __syncthreads();
  }
  #pragma unroll
  for (int mt = 0; mt < 4; ++mt) {
    #pragma unroll
    for (int nt = 0; nt < 4; ++nt) {
      int col = col0 + wn * 64 + nt * 16 + m15;
      float bv = bias[col];
      #pragma unroll
      for (int r = 0; r < 4; ++r) {
        int row = row0 + wm * 64 + mt * 16 + quad * 4 + r;
        int orow = swap_rows ? ((row & 63) * 256 + (row >> 6)) : row;
        Cout[(size_t)orow * 1024 + col] = acc[mt][nt][r] + bv;
      }
    }
  }
}

// ---------------- fused pipelined recurrent kernel (ALL layers) ----------------
// 256 WGs = 4 layers x [4 row-blocks(16 rows) x 16 col-blocks(64 cols)].
// Exactly 1 WG/CU (VGPR-limited) -> grid <= capacity -> all co-resident.
// Per WG per step t:
//   A: publish z[t] slice (relaxed agent atomic stores -> __syncthreads vmcnt
//      drain -> flag = t+1). The same drain covers h_{t-1} persist stores, so
//      flag value v also promises h_{v-2} of this layer is readable.
//   B: x-part of z[t+1]: poll layer-(l-1) flag >= t+3 (per-thread, pipeline-full
//      => immediate), stage x_{t+1} tile -> LDS, 32 MFMAs with resident Wx frags.
//      This overlaps the peers' z[t] publish latency.
//   C: poll own-group peer flags >= t+1 (per-thread), ring z[t] via 8B agent
//      atomic loads (bypass L2 -> ring reuse is coherent), LN stats via 16-lane
//      shuffles, tanh -> swizzled LDS h tile.
//   D: persist h_t (bf16 agent atomics to X[l]; layer 3 also fp32 -> out_x),
//      32 MFMAs h_t @ Wh^T accumulating into z[t+1].
// Z ring safety: producer overwrites slot s=t%4 at A(t+4), which is after its
// C(t+3) poll saw every peer's flag t+4, published after that peer's C(t+2),
// i.e. long after the peer consumed slot s at C(t). Skew bound << RING.
__launch_bounds__(256, 1)
__global__ void k_fused(const float* __restrict__ inp,              // [B][T][H] fp32
                        const unsigned short* __restrict__ Whb_all, // [L][H][H] bf16
                        const unsigned short* __restrict__ Wxb_all, // [L][H][H] bf16
                        const float* __restrict__ bx_all,           // [L][H]
                        const float* __restrict__ lng_all,
                        const float* __restrict__ lnb_all,
                        unsigned short* Xbuf,                       // [L][T][B][H] bf16 (layer outputs)
                        float* Zr,                                  // [L][RING][4][16][1024] fp32
                        int* flags,                                 // [L][64][32] (128B padded)
                        float* __restrict__ outx)                   // [B][T][H] fp32
{
  __shared__ short hs[16 * 1024];      // 32 KB swizzled h (bf16)
  __shared__ short xs[16 * 1024];      // 32 KB swizzled x (bf16)
  __shared__ float sG[1024], sB[1024]; // 8 KB

  const int tid = threadIdx.x, lane = tid & 63, w = tid >> 6;
  const int bid = blockIdx.x;
  const int l = bid >> 6, rb = (bid >> 4) & 3, cb = bid & 15;
  const int r0 = rb * 16, c0 = cb * 64;
  const int m15 = lane & 15, quad = lane >> 4;
  const int myrow = 4 * w + quad;      // LN/stage phase: wave w owns rows 4w..4w+3
  const int chunk = m15;               // lane owns 64-col chunk of its row

  for (int i = tid; i < 1024; i += 256) { sG[i] = lng_all[l * H_ + i]; sB[i] = lnb_all[l * H_ + i]; }

  // resident weight fragments: wave w covers output cols c0+16w..+15
  v8s bh[32], bx8[32];
  {
    const unsigned short* wr = Whb_all + ((size_t)l * H_ + c0 + w * 16 + m15) * H_ + quad * 8;
    #pragma unroll
    for (int ks = 0; ks < 32; ++ks) bh[ks] = *(const v8s*)(wr + ks * 32);
    const unsigned short* wx = Wxb_all + ((size_t)l * H_ + c0 + w * 16 + m15) * H_ + quad * 8;
    #pragma unroll
    for (int ks = 0; ks < 32; ++ks) bx8[ks] = *(const v8s*)(wx + ks * 32);
  }

  const float bias = bx_all[l * H_ + c0 + w * 16 + m15];
  int* myfz = flags + ((l * 64 + rb * 16 + cb) << 5);
  const int* peer_fz = flags + ((l * 64 + rb * 16 + chunk) << 5);   // produces my z cols
  const int* prev_fz = (l > 0) ? flags + (((l - 1) * 64 + rb * 16 + chunk) << 5) : (const int*)nullptr;

  const size_t TBH = (size_t)T_ * B_ * H_;
  unsigned short* Xout = Xbuf + (size_t)l * TBH;
  const unsigned short* Xin = (l > 0) ? Xbuf + (size_t)(l - 1) * TBH : (const unsigned short*)nullptr;
  float* Zl = Zr + (size_t)l * RING * 4 * 16 * 1024;

  // stage x[t1] rows r0..r0+15 into xs (swizzled). Per-thread gated by its own
  // inter-layer flag (producer of cols chunk*64.. is col-block cb'=chunk).
  auto stage_x = [&](int t1) {
    if (l == 0) {
      const float* src = inp + ((size_t)(r0 + myrow) * T_ + t1) * H_ + chunk * 64;
      #pragma unroll
      for (int g8 = 0; g8 < 8; ++g8) {
        float4 q0 = *(const float4*)(src + g8 * 8);
        float4 q1 = *(const float4*)(src + g8 * 8 + 4);
        v8s hp;
        hp[0] = (short)f2bf(q0.x); hp[1] = (short)f2bf(q0.y);
        hp[2] = (short)f2bf(q0.z); hp[3] = (short)f2bf(q0.w);
        hp[4] = (short)f2bf(q1.x); hp[5] = (short)f2bf(q1.y);
        hp[6] = (short)f2bf(q1.z); hp[7] = (short)f2bf(q1.w);
        *(v8s*)&xs[hswz(myrow, chunk * 8 + g8)] = hp;
      }
    } else {
      // plain 16B loads: addresses monotonic in t within this dispatch ->
      // guaranteed L2 first-touch after the flag -> fresh from L3.
      const unsigned short* src = Xin + ((size_t)t1 * B_ + r0 + myrow) * H_ + chunk * 64;
      #pragma unroll
      for (int g8 = 0; g8 < 8; ++g8)
        *(v8s*)&xs[hswz(myrow, chunk * 8 + g8)] = *(const v8s*)(src + g8 * 8);
    }
  };

  // ---- prologue: z[0] = bx + x_0 @ Wx^T ----
  if (l > 0) poll_ge(prev_fz, 2);
  stage_x(0);
  __syncthreads();
  v4f acc = (v4f){bias, bias, bias, bias};
  #pragma unroll
  for (int ks = 0; ks < 32; ++ks) {
    v8s a = *(const v8s*)&xs[hswz(m15, ks * 4 + quad)];
    acc = __builtin_amdgcn_mfma_f32_16x16x32_bf16(a, bx8[ks], acc, 0, 0, 0);
  }

  for (int t = 0; t < T_; ++t) {
    // ---- A: publish z[t] ----
    float* zo = Zl + (size_t)((t & (RING - 1)) * 4 + rb) * 16 * 1024;
    #pragma unroll
    for (int r = 0; r < 4; ++r)
      __hip_atomic_store(&zo[(size_t)(quad * 4 + r) * H_ + c0 + w * 16 + m15], acc[r],
                         __ATOMIC_RELAXED, __HIP_MEMORY_SCOPE_AGENT);
    __syncthreads();   // vmcnt(0) all waves: z[t] + h_{t-1} persist at coherence point
    if (tid == 0)
      __hip_atomic_store(myfz, t + 1, __ATOMIC_RELAXED, __HIP_MEMORY_SCOPE_AGENT);

    // ---- B: x-part of z[t+1] (overlaps peers' publish) ----
    if (t < T_ - 1) {
      if (l > 0) poll_ge(prev_fz, t + 3);   // h_{l-1}[t+1] readable when flag >= t+3
      stage_x(t + 1);
      __syncthreads();
      acc = (v4f){bias, bias, bias, bias};
      #pragma unroll
      for (int ks = 0; ks < 32; ++ks) {
        v8s a = *(const v8s*)&xs[hswz(m15, ks * 4 + quad)];
        acc = __builtin_amdgcn_mfma_f32_16x16x32_bf16(a, bx8[ks], acc, 0, 0, 0);
      }
    }

    // ---- C: consume z[t] -> h_t ----
    poll_ge(peer_fz, t + 1);
    const u64t* zp = (const u64t*)(zo + (size_t)myrow * H_ + chunk * 64);
    float2 zr2[32];
    #pragma unroll
    for (int j = 0; j < 32; ++j) {
      union { u64t u; float2 f; } cv;
      cv.u = __hip_atomic_load(zp + j, __ATOMIC_RELAXED, __HIP_MEMORY_SCOPE_AGENT);
      zr2[j] = cv.f;
    }
    float s = 0.f, s2 = 0.f;
    #pragma unroll
    for (int j = 0; j < 32; ++j) {
      s  += zr2[j].x + zr2[j].y;
      s2 += zr2[j].x * zr2[j].x + zr2[j].y * zr2[j].y;
    }
    #pragma unroll
    for (int m = 1; m < 16; m <<= 1) { s += __shfl_xor(s, m); s2 += __shfl_xor(s2, m); }
    float mu = s * (1.f / 1024.f);
    float var = s2 * (1.f / 1024.f) - mu * mu;
    float rs = rsqrtf(var + LN_EPS);
    #pragma unroll
    for (int g8 = 0; g8 < 8; ++g8) {
      v8s hp;
      #pragma unroll
      for (int e = 0; e < 8; ++e) {
        int colg = chunk * 64 + g8 * 8 + e;
        float zv = (e & 1) ? zr2[g8 * 4 + (e >> 1)].y : zr2[g8 * 4 + (e >> 1)].x;
        float hv = tanh_fast((zv - mu) * rs * sG[colg] + sB[colg]);
        hp[e] = (short)f2bf(hv);
      }
      *(v8s*)&hs[hswz(myrow, chunk * 8 + g8)] = hp;
    }
    __syncthreads();   // hs complete (16 rows x 1024)

    // ---- D: persist h_t ; h-MFMA into z[t+1] ----
    {
      int row = tid >> 4, ci = tid & 15;
      int colbase = c0 + ci * 4;
      const short* hp = &hs[hswz(row, colbase >> 3) + (ci & 1) * 4];
      union { unsigned short u[4]; u64t q; } pk;
      pk.u[0] = (unsigned short)hp[0]; pk.u[1] = (unsigned short)hp[1];
      pk.u[2] = (unsigned short)hp[2]; pk.u[3] = (unsigned short)hp[3];
      u64t* xdst = (u64t*)(Xout + ((size_t)t * B_ + r0 + row) * H_ + colbase);
      if (l < L_ - 1) {
        __hip_atomic_store(xdst, pk.q, __ATOMIC_RELAXED, __HIP_MEMORY_SCOPE_AGENT);
      } else {
        *xdst = pk.q;   // consumed only by post-kernel y-GEMM (dispatch boundary flushes)
        float4 f;
        f.x = bf2f(pk.u[0]); f.y = bf2f(pk.u[1]); f.z = bf2f(pk.u[2]); f.w = bf2f(pk.u[3]);
        *(float4*)(outx + ((size_t)(r0 + row) * T_ + t) * H_ + colbase) = f;
      }
    }
    if (t < T_ - 1) {
      #pragma unroll
      for (int ks = 0; ks < 32; ++ks) {
        v8s a = *(const v8s*)&hs[hswz(m15, ks * 4 + quad)];
        acc = __builtin_amdgcn_mfma_f32_16x16x32_bf16(a, bh[ks], acc, 0, 0, 0);
      }
    }
  }
  __syncthreads();   // drain h_{T-1} persist
  if (tid == 0)
    __hip_atomic_store(myfz, T_ + 1, __ATOMIC_RELAXED, __HIP_MEMORY_SCOPE_AGENT);
}

extern "C" void kernel_launch(void* const* d_in, const int* in_sizes, int n_in,
                              void* d_out, int out_size, void* d_ws, size_t ws_size,
                              hipStream_t stream) {
  const float* inp = (const float*)d_in[0];
  const float* Wx  = (const float*)d_in[1];
  const float* bx  = (const float*)d_in[2];
  const float* Wh  = (const float*)d_in[3];
  const float* lng = (const float*)d_in[4];
  const float* lnb = (const float*)d_in[5];
  const float* Wy  = (const float*)d_in[6];
  const float* by  = (const float*)d_in[7];
  float* out_x = (float*)d_out;
  float* out_y = out_x + (size_t)B_ * T_ * H_;

  char* ws = (char*)d_ws;
  unsigned short* Whb  = (unsigned short*)(ws);                        // 8 MB
  unsigned short* Wxb  = (unsigned short*)(ws + ((size_t)8 << 20));    // 8 MB
  unsigned short* Wyb  = (unsigned short*)(ws + ((size_t)16 << 20));   // 2 MB
  int* flags           = (int*)(ws + ((size_t)18 << 20));              // 32 KB (padded)
  float* Zr            = (float*)(ws + ((size_t)19 << 20));            // 4 MB ring
  unsigned short* Xbuf = (unsigned short*)(ws + ((size_t)23 << 20));   // 128 MB (total 151 MB)

  hipMemsetAsync(flags, 0, (size_t)L_ * 64 * 32 * sizeof(int), stream);
  k_f2b<<<1024, 256, 0, stream>>>(Wh, Whb, (L_ * H_ * H_) / 4);
  k_f2b<<<1024, 256, 0, stream>>>(Wx, Wxb, (L_ * H_ * H_) / 4);
  k_f2b<<<256, 256, 0, stream>>>(Wy, Wyb, (O_ * H_) / 4);

  k_fused<<<L_ * 64, 256, 0, stream>>>(inp, Whb, Wxb, bx, lng, lnb,
                                       Xbuf, Zr, flags, out_x);

  k_gemm<<<1024, 256, 0, stream>>>(Xbuf + (size_t)(L_ - 1) * T_ * B_ * H_,
                                   Wyb, by, out_y, 1);
}